// Round 1
// baseline (567.214 us; speedup 1.0000x reference)
//
#include <hip/hip_runtime.h>
#include <cstdint>
#include <cstddef>

#define D_MODEL 256
#define D_STATE 64
#define HEADDIM 64
#define D_INNER 512
#define NHEADS 8
#define D_XBC 640
#define NPROJ 1160
#define BATCH 64
#define SEQ 250
#define ROWS (BATCH * SEQ) /* 16000 */
#define KIN 240            /* effective K for gemm1: u cols 240..255 are zero pad */

__device__ __forceinline__ float readlane_f(float v, int lane) {
    return __uint_as_float(__builtin_amdgcn_readlane(__float_as_uint(v), lane));
}
__device__ __forceinline__ float silu_f(float x) { return x * (1.f / (1.f + __expf(-x))); }

// ---------------------------------------------------------------------------
// Kernel 1: zxbcdt[16000][1160] = u @ W_in, u built on the fly from x (K=240)
// ---------------------------------------------------------------------------
__global__ __launch_bounds__(256) void gemm1_kernel(const float* __restrict__ x,
                                                    const float* __restrict__ Win,
                                                    float* __restrict__ zxbcdt) {
    __shared__ float As[64][17];
    __shared__ float Bs[16][64];
    const int tid = threadIdx.x;
    const int tx = tid & 15, ty = tid >> 4;
    const int rowBase = blockIdx.y * 64;
    const int colBase = blockIdx.x * 64;
    float acc[4][4] = {};

    for (int k0 = 0; k0 < KIN; k0 += 16) {
#pragma unroll
        for (int i = 0; i < 4; i++) {
            int flat = tid + i * 256;
            int ar = flat >> 4, ak = flat & 15;
            int grow = rowBase + ar;
            int bb = grow / SEQ;
            int tt = grow - bb * SEQ;
            As[ar][ak] = x[bb * 60000 + tt * 240 + k0 + ak];
        }
#pragma unroll
        for (int i = 0; i < 4; i++) {
            int flat = tid + i * 256;
            int bk = flat >> 6, bc = flat & 63;
            int gcol = colBase + bc;
            Bs[bk][bc] = (gcol < NPROJ) ? Win[(k0 + bk) * NPROJ + gcol] : 0.f;
        }
        __syncthreads();
#pragma unroll
        for (int kk = 0; kk < 16; kk++) {
            float a[4], b[4];
#pragma unroll
            for (int i = 0; i < 4; i++) a[i] = As[ty * 4 + i][kk];
#pragma unroll
            for (int j = 0; j < 4; j++) b[j] = Bs[kk][tx * 4 + j];
#pragma unroll
            for (int i = 0; i < 4; i++)
#pragma unroll
                for (int j = 0; j < 4; j++) acc[i][j] = fmaf(a[i], b[j], acc[i][j]);
        }
        __syncthreads();
    }
#pragma unroll
    for (int i = 0; i < 4; i++) {
        int grow = rowBase + ty * 4 + i;
#pragma unroll
        for (int j = 0; j < 4; j++) {
            int gcol = colBase + tx * 4 + j;
            if (gcol < NPROJ) zxbcdt[(size_t)grow * NPROJ + gcol] = acc[i][j];
        }
    }
}

// ---------------------------------------------------------------------------
// Kernel 2: causal depthwise conv4 + bias + SiLU over xBC cols; softplus(dt)
// ---------------------------------------------------------------------------
__global__ __launch_bounds__(256) void conv_kernel(const float* __restrict__ zxbcdt,
                                                   const float* __restrict__ conv_w,
                                                   const float* __restrict__ conv_b,
                                                   const float* __restrict__ dt_bias,
                                                   float* __restrict__ xc,
                                                   float* __restrict__ dtp) {
    const int NCONV = ROWS * D_XBC;
    int idx = blockIdx.x * 256 + threadIdx.x;
    if (idx < NCONV) {
        int row = idx / D_XBC;
        int ch = idx - row * D_XBC;
        int t = row % SEQ;
        float accv = conv_b[ch];
#pragma unroll
        for (int k = 0; k < 4; k++) {
            int tt = t - 3 + k;
            if (tt >= 0)
                accv = fmaf(zxbcdt[(size_t)(row - 3 + k) * NPROJ + D_INNER + ch],
                            conv_w[ch * 4 + k], accv);
        }
        xc[idx] = silu_f(accv);
    } else if (idx < NCONV + ROWS * NHEADS) {
        int r = idx - NCONV;
        int row = r >> 3, h = r & 7;
        float v = zxbcdt[(size_t)row * NPROJ + (D_INNER + D_XBC) + h] + dt_bias[h];
        dtp[r] = (v > 20.f) ? v : __logf(1.f + __expf(v));
    }
}

// ---------------------------------------------------------------------------
// Kernel 3: SSM scan. One wave per (batch, head). lane = p (headdim).
// State h[p][n] lives in 64 VGPRs per lane; B/C broadcast via v_readlane.
// ---------------------------------------------------------------------------
__global__ __launch_bounds__(64) void scan_kernel(const float* __restrict__ xc,
                                                  const float* __restrict__ dtp,
                                                  const float* __restrict__ A_log,
                                                  const float* __restrict__ Dvec,
                                                  float* __restrict__ yout) {
    const int bh = blockIdx.x;
    const int b = bh >> 3, h = bh & 7;
    const int lane = threadIdx.x;
    const float A = -__expf(A_log[h]);
    const float Dh = Dvec[h];
    float hreg[64];
#pragma unroll
    for (int n = 0; n < 64; n++) hreg[n] = 0.f;
    const float* xcb = xc + (size_t)b * SEQ * D_XBC;
    const float* dtb = dtp + b * SEQ * NHEADS + h;
    float* yb = yout + (size_t)b * SEQ * D_INNER + h * HEADDIM + lane;

    for (int t = 0; t < SEQ; t++) {
        const float* rp = xcb + t * D_XBC;
        float xv = rp[h * HEADDIM + lane];
        float Bv = rp[D_INNER + lane];
        float Cv = rp[D_INNER + D_STATE + lane];
        float dtv = dtb[t * NHEADS];
        float decay = __expf(dtv * A);
        float coef = dtv * xv;
        float acc = 0.f;
#pragma unroll
        for (int n = 0; n < 64; n++) {
            float Bn = readlane_f(Bv, n);
            float Cn = readlane_f(Cv, n);
            hreg[n] = fmaf(hreg[n], decay, coef * Bn);
            acc = fmaf(hreg[n], Cn, acc);
        }
        yb[t * D_INNER] = fmaf(Dh, xv, acc);
    }
}

// ---------------------------------------------------------------------------
// Kernel 4: per-row RMS scale of g = y * silu(z). One wave per row.
// ---------------------------------------------------------------------------
__global__ __launch_bounds__(256) void rms_kernel(const float* __restrict__ yout,
                                                  const float* __restrict__ zx,
                                                  float* __restrict__ rms) {
    const int wid = threadIdx.x >> 6, lane = threadIdx.x & 63;
    const int row = blockIdx.x * 4 + wid;
    const float* yr = yout + (size_t)row * D_INNER;
    const float* zr = zx + (size_t)row * NPROJ;
    float s = 0.f;
#pragma unroll
    for (int j = 0; j < 8; j++) {
        int i = j * 64 + lane;
        float g = yr[i] * silu_f(zr[i]);
        s = fmaf(g, g, s);
    }
#pragma unroll
    for (int o = 32; o; o >>= 1) s += __shfl_xor(s, o, 64);
    if (lane == 0) rms[row] = rsqrtf(s * (1.f / 512.f) + 1e-5f);
}

// ---------------------------------------------------------------------------
// Kernel 5: out = selu( (g*rms*norm_w) @ W_out )[:, :240]
// A-tile (gated+normed rows) built on the fly.
// ---------------------------------------------------------------------------
__global__ __launch_bounds__(256) void gemm2_kernel(const float* __restrict__ yout,
                                                    const float* __restrict__ zx,
                                                    const float* __restrict__ rms,
                                                    const float* __restrict__ norm_w,
                                                    const float* __restrict__ Wout,
                                                    float* __restrict__ out) {
    __shared__ float As[64][17];
    __shared__ float Bs[16][64];
    const int tid = threadIdx.x;
    const int tx = tid & 15, ty = tid >> 4;
    const int rowBase = blockIdx.y * 64;
    const int colBase = blockIdx.x * 64;
    float acc[4][4] = {};

    for (int k0 = 0; k0 < D_INNER; k0 += 16) {
#pragma unroll
        for (int i = 0; i < 4; i++) {
            int flat = tid + i * 256;
            int ar = flat >> 4, ak = flat & 15;
            int grow = rowBase + ar;
            int kk = k0 + ak;
            float g = yout[(size_t)grow * D_INNER + kk] * silu_f(zx[(size_t)grow * NPROJ + kk]);
            As[ar][ak] = g * rms[grow] * norm_w[kk];
        }
#pragma unroll
        for (int i = 0; i < 4; i++) {
            int flat = tid + i * 256;
            int bk = flat >> 6, bc = flat & 63;
            Bs[bk][bc] = Wout[(k0 + bk) * D_MODEL + colBase + bc];
        }
        __syncthreads();
#pragma unroll
        for (int kk = 0; kk < 16; kk++) {
            float a[4], b[4];
#pragma unroll
            for (int i = 0; i < 4; i++) a[i] = As[ty * 4 + i][kk];
#pragma unroll
            for (int j = 0; j < 4; j++) b[j] = Bs[kk][tx * 4 + j];
#pragma unroll
            for (int i = 0; i < 4; i++)
#pragma unroll
                for (int j = 0; j < 4; j++) acc[i][j] = fmaf(a[i], b[j], acc[i][j]);
        }
        __syncthreads();
    }
    const float SC = 1.0507009873554805f, AL = 1.6732632423543772f;
#pragma unroll
    for (int i = 0; i < 4; i++) {
        int grow = rowBase + ty * 4 + i;
#pragma unroll
        for (int j = 0; j < 4; j++) {
            int gcol = colBase + tx * 4 + j;
            if (gcol < 240) {
                float v = acc[i][j];
                v = (v > 0.f) ? SC * v : SC * AL * (__expf(v) - 1.f);
                out[(size_t)grow * 240 + gcol] = v;
            }
        }
    }
}

// ---------------------------------------------------------------------------
extern "C" void kernel_launch(void* const* d_in, const int* in_sizes, int n_in,
                              void* d_out, int out_size, void* d_ws, size_t ws_size,
                              hipStream_t stream) {
    const float* x = (const float*)d_in[0];
    const float* W_in = (const float*)d_in[1];
    const float* conv_w = (const float*)d_in[2];
    const float* conv_b = (const float*)d_in[3];
    const float* A_log = (const float*)d_in[4];
    const float* dt_bias = (const float*)d_in[5];
    const float* Dv = (const float*)d_in[6];
    const float* norm_w = (const float*)d_in[7];
    const float* W_out = (const float*)d_in[8];
    float* out = (float*)d_out;

    float* ws = (float*)d_ws;
    float* zxbcdt = ws;                                  // 16000*1160
    float* xc = zxbcdt + (size_t)ROWS * NPROJ;           // 16000*640
    float* dtp = xc + (size_t)ROWS * D_XBC;              // 16000*8
    float* yout = dtp + (size_t)ROWS * NHEADS;           // 16000*512
    float* rms = yout + (size_t)ROWS * D_INNER;          // 16000

    gemm1_kernel<<<dim3(19, 250), 256, 0, stream>>>(x, W_in, zxbcdt);

    int conv_total = ROWS * D_XBC + ROWS * NHEADS;
    conv_kernel<<<dim3((conv_total + 255) / 256), 256, 0, stream>>>(zxbcdt, conv_w, conv_b,
                                                                    dt_bias, xc, dtp);

    scan_kernel<<<dim3(BATCH * NHEADS), 64, 0, stream>>>(xc, dtp, A_log, Dv, yout);

    rms_kernel<<<dim3(ROWS / 4), 256, 0, stream>>>(yout, zxbcdt, rms);

    gemm2_kernel<<<dim3(4, 250), 256, 0, stream>>>(yout, zxbcdt, rms, norm_w, W_out, out);
}

// Round 2
// 544.730 us; speedup vs baseline: 1.0413x; 1.0413x over previous
//
#include <hip/hip_runtime.h>
#include <cstdint>
#include <cstddef>

#define D_MODEL 256
#define D_STATE 64
#define HEADDIM 64
#define D_INNER 512
#define NHEADS 8
#define D_XBC 640
#define NPROJ 1160
#define BATCH 64
#define SEQ 250
#define ROWS (BATCH * SEQ) /* 16000 */
#define KIN 240            /* effective K for gemm1: u cols 240..255 are zero pad */

__device__ __forceinline__ float readlane_f(float v, int lane) {
    return __uint_as_float(__builtin_amdgcn_readlane(__float_as_uint(v), lane));
}
__device__ __forceinline__ float silu_f(float x) { return x * (1.f / (1.f + __expf(-x))); }

// ---------------------------------------------------------------------------
// Kernel 1: zxbcdt[16000][1160] = u @ W_in, u built on the fly from x (K=240)
// ---------------------------------------------------------------------------
__global__ __launch_bounds__(256) void gemm1_kernel(const float* __restrict__ x,
                                                    const float* __restrict__ Win,
                                                    float* __restrict__ zxbcdt) {
    __shared__ float As[64][17];
    __shared__ float Bs[16][64];
    const int tid = threadIdx.x;
    const int tx = tid & 15, ty = tid >> 4;
    const int rowBase = blockIdx.y * 64;
    const int colBase = blockIdx.x * 64;
    float acc[4][4] = {};

    for (int k0 = 0; k0 < KIN; k0 += 16) {
#pragma unroll
        for (int i = 0; i < 4; i++) {
            int flat = tid + i * 256;
            int ar = flat >> 4, ak = flat & 15;
            int grow = rowBase + ar;
            int bb = grow / SEQ;
            int tt = grow - bb * SEQ;
            As[ar][ak] = x[bb * 60000 + tt * 240 + k0 + ak];
        }
#pragma unroll
        for (int i = 0; i < 4; i++) {
            int flat = tid + i * 256;
            int bk = flat >> 6, bc = flat & 63;
            int gcol = colBase + bc;
            Bs[bk][bc] = (gcol < NPROJ) ? Win[(k0 + bk) * NPROJ + gcol] : 0.f;
        }
        __syncthreads();
#pragma unroll
        for (int kk = 0; kk < 16; kk++) {
            float a[4], b[4];
#pragma unroll
            for (int i = 0; i < 4; i++) a[i] = As[ty * 4 + i][kk];
#pragma unroll
            for (int j = 0; j < 4; j++) b[j] = Bs[kk][tx * 4 + j];
#pragma unroll
            for (int i = 0; i < 4; i++)
#pragma unroll
                for (int j = 0; j < 4; j++) acc[i][j] = fmaf(a[i], b[j], acc[i][j]);
        }
        __syncthreads();
    }
#pragma unroll
    for (int i = 0; i < 4; i++) {
        int grow = rowBase + ty * 4 + i;
#pragma unroll
        for (int j = 0; j < 4; j++) {
            int gcol = colBase + tx * 4 + j;
            if (gcol < NPROJ) zxbcdt[(size_t)grow * NPROJ + gcol] = acc[i][j];
        }
    }
}

// ---------------------------------------------------------------------------
// Kernel 2: causal depthwise conv4 + bias + SiLU over xBC cols; softplus(dt)
// ---------------------------------------------------------------------------
__global__ __launch_bounds__(256) void conv_kernel(const float* __restrict__ zxbcdt,
                                                   const float* __restrict__ conv_w,
                                                   const float* __restrict__ conv_b,
                                                   const float* __restrict__ dt_bias,
                                                   float* __restrict__ xc,
                                                   float* __restrict__ dtp) {
    const int NCONV = ROWS * D_XBC;
    int idx = blockIdx.x * 256 + threadIdx.x;
    if (idx < NCONV) {
        int row = idx / D_XBC;
        int ch = idx - row * D_XBC;
        int t = row % SEQ;
        float accv = conv_b[ch];
#pragma unroll
        for (int k = 0; k < 4; k++) {
            int tt = t - 3 + k;
            if (tt >= 0)
                accv = fmaf(zxbcdt[(size_t)(row - 3 + k) * NPROJ + D_INNER + ch],
                            conv_w[ch * 4 + k], accv);
        }
        xc[idx] = silu_f(accv);
    } else if (idx < NCONV + ROWS * NHEADS) {
        int r = idx - NCONV;
        int row = r >> 3, h = r & 7;
        float v = zxbcdt[(size_t)row * NPROJ + (D_INNER + D_XBC) + h] + dt_bias[h];
        dtp[r] = (v > 20.f) ? v : __logf(1.f + __expf(v));
    }
}

// ---------------------------------------------------------------------------
// Kernel 3: SSM scan v2. One block (4 waves) per (batch, head); lane = p.
// State dim n split across waves (16 each); prefetched loads; LDS combine.
// ---------------------------------------------------------------------------
__global__ __launch_bounds__(256) void scan_kernel(const float* __restrict__ xc,
                                                   const float* __restrict__ dtp,
                                                   const float* __restrict__ A_log,
                                                   const float* __restrict__ Dvec,
                                                   float* __restrict__ yout) {
    const int bh = blockIdx.x;
    const int b = bh >> 3, h = bh & 7;
    const int tid = threadIdx.x;
    const int lane = tid & 63;
    const int w = tid >> 6;   // wave id 0..3; owns states n0..n0+15
    const int n0 = w * 16;
    const float A = -__expf(A_log[h]);
    const float Dh = Dvec[h];
    float hreg[16];
#pragma unroll
    for (int n = 0; n < 16; n++) hreg[n] = 0.f;
    __shared__ float part[4][64];

    const float* xcb = xc + (size_t)b * SEQ * D_XBC;
    const float* dtb = dtp + b * SEQ * NHEADS + h;
    float* yb = yout + (size_t)b * SEQ * D_INNER + h * HEADDIM + lane;

    // prefetch t=0
    float xv = xcb[h * HEADDIM + lane];
    float Bv = xcb[D_INNER + lane];
    float Cv = xcb[D_INNER + D_STATE + lane];
    float dtv = dtb[0];

    for (int t = 0; t < SEQ; t++) {
        // prefetch t+1 (clamped so the last iteration stays branch-free)
        int tn = (t + 1 < SEQ) ? (t + 1) : (SEQ - 1);
        const float* rq = xcb + tn * D_XBC;
        float xv_n = rq[h * HEADDIM + lane];
        float Bv_n = rq[D_INNER + lane];
        float Cv_n = rq[D_INNER + D_STATE + lane];
        float dtv_n = dtb[tn * NHEADS];

        float decay = __expf(dtv * A);
        float coef = dtv * xv;
        float acc[4] = {0.f, 0.f, 0.f, 0.f};
#pragma unroll
        for (int n = 0; n < 16; n++) {
            float Bn = readlane_f(Bv, n0 + n);
            float Cn = readlane_f(Cv, n0 + n);
            hreg[n] = fmaf(hreg[n], decay, coef * Bn);
            acc[n & 3] = fmaf(hreg[n], Cn, acc[n & 3]);
        }
        part[w][lane] = (acc[0] + acc[1]) + (acc[2] + acc[3]);
        __syncthreads();
        if (w == 0) {
            float y = (part[0][lane] + part[1][lane]) + (part[2][lane] + part[3][lane]);
            yb[t * D_INNER] = fmaf(Dh, xv, y);
        }
        __syncthreads();
        xv = xv_n; Bv = Bv_n; Cv = Cv_n; dtv = dtv_n;
    }
}

// ---------------------------------------------------------------------------
// Kernel 4: per-row RMS scale of g = y * silu(z). One wave per row.
// ---------------------------------------------------------------------------
__global__ __launch_bounds__(256) void rms_kernel(const float* __restrict__ yout,
                                                  const float* __restrict__ zx,
                                                  float* __restrict__ rms) {
    const int wid = threadIdx.x >> 6, lane = threadIdx.x & 63;
    const int row = blockIdx.x * 4 + wid;
    const float* yr = yout + (size_t)row * D_INNER;
    const float* zr = zx + (size_t)row * NPROJ;
    float s = 0.f;
#pragma unroll
    for (int j = 0; j < 8; j++) {
        int i = j * 64 + lane;
        float g = yr[i] * silu_f(zr[i]);
        s = fmaf(g, g, s);
    }
#pragma unroll
    for (int o = 32; o; o >>= 1) s += __shfl_xor(s, o, 64);
    if (lane == 0) rms[row] = rsqrtf(s * (1.f / 512.f) + 1e-5f);
}

// ---------------------------------------------------------------------------
// Kernel 5: out = selu( (g*rms*norm_w) @ W_out )[:, :240]
// A-tile (gated+normed rows) built on the fly.
// ---------------------------------------------------------------------------
__global__ __launch_bounds__(256) void gemm2_kernel(const float* __restrict__ yout,
                                                    const float* __restrict__ zx,
                                                    const float* __restrict__ rms,
                                                    const float* __restrict__ norm_w,
                                                    const float* __restrict__ Wout,
                                                    float* __restrict__ out) {
    __shared__ float As[64][17];
    __shared__ float Bs[16][64];
    const int tid = threadIdx.x;
    const int tx = tid & 15, ty = tid >> 4;
    const int rowBase = blockIdx.y * 64;
    const int colBase = blockIdx.x * 64;
    float acc[4][4] = {};

    for (int k0 = 0; k0 < D_INNER; k0 += 16) {
#pragma unroll
        for (int i = 0; i < 4; i++) {
            int flat = tid + i * 256;
            int ar = flat >> 4, ak = flat & 15;
            int grow = rowBase + ar;
            int kk = k0 + ak;
            float g = yout[(size_t)grow * D_INNER + kk] * silu_f(zx[(size_t)grow * NPROJ + kk]);
            As[ar][ak] = g * rms[grow] * norm_w[kk];
        }
#pragma unroll
        for (int i = 0; i < 4; i++) {
            int flat = tid + i * 256;
            int bk = flat >> 6, bc = flat & 63;
            Bs[bk][bc] = Wout[(k0 + bk) * D_MODEL + colBase + bc];
        }
        __syncthreads();
#pragma unroll
        for (int kk = 0; kk < 16; kk++) {
            float a[4], b[4];
#pragma unroll
            for (int i = 0; i < 4; i++) a[i] = As[ty * 4 + i][kk];
#pragma unroll
            for (int j = 0; j < 4; j++) b[j] = Bs[kk][tx * 4 + j];
#pragma unroll
            for (int i = 0; i < 4; i++)
#pragma unroll
                for (int j = 0; j < 4; j++) acc[i][j] = fmaf(a[i], b[j], acc[i][j]);
        }
        __syncthreads();
    }
    const float SC = 1.0507009873554805f, AL = 1.6732632423543772f;
#pragma unroll
    for (int i = 0; i < 4; i++) {
        int grow = rowBase + ty * 4 + i;
#pragma unroll
        for (int j = 0; j < 4; j++) {
            int gcol = colBase + tx * 4 + j;
            if (gcol < 240) {
                float v = acc[i][j];
                v = (v > 0.f) ? SC * v : SC * AL * (__expf(v) - 1.f);
                out[(size_t)grow * 240 + gcol] = v;
            }
        }
    }
}

// ---------------------------------------------------------------------------
extern "C" void kernel_launch(void* const* d_in, const int* in_sizes, int n_in,
                              void* d_out, int out_size, void* d_ws, size_t ws_size,
                              hipStream_t stream) {
    const float* x = (const float*)d_in[0];
    const float* W_in = (const float*)d_in[1];
    const float* conv_w = (const float*)d_in[2];
    const float* conv_b = (const float*)d_in[3];
    const float* A_log = (const float*)d_in[4];
    const float* dt_bias = (const float*)d_in[5];
    const float* Dv = (const float*)d_in[6];
    const float* norm_w = (const float*)d_in[7];
    const float* W_out = (const float*)d_in[8];
    float* out = (float*)d_out;

    float* ws = (float*)d_ws;
    float* zxbcdt = ws;                                  // 16000*1160
    float* xc = zxbcdt + (size_t)ROWS * NPROJ;           // 16000*640
    float* dtp = xc + (size_t)ROWS * D_XBC;              // 16000*8
    float* yout = dtp + (size_t)ROWS * NHEADS;           // 16000*512
    float* rms = yout + (size_t)ROWS * D_INNER;          // 16000

    gemm1_kernel<<<dim3(19, 250), 256, 0, stream>>>(x, W_in, zxbcdt);

    int conv_total = ROWS * D_XBC + ROWS * NHEADS;
    conv_kernel<<<dim3((conv_total + 255) / 256), 256, 0, stream>>>(zxbcdt, conv_w, conv_b,
                                                                    dt_bias, xc, dtp);

    scan_kernel<<<dim3(BATCH * NHEADS), 256, 0, stream>>>(xc, dtp, A_log, Dv, yout);

    rms_kernel<<<dim3(ROWS / 4), 256, 0, stream>>>(yout, zxbcdt, rms);

    gemm2_kernel<<<dim3(4, 250), 256, 0, stream>>>(yout, zxbcdt, rms, norm_w, W_out, out);
}

// Round 3
// 430.340 us; speedup vs baseline: 1.3181x; 1.2658x over previous
//
#include <hip/hip_runtime.h>
#include <cstdint>
#include <cstddef>

#define D_MODEL 256
#define D_STATE 64
#define HEADDIM 64
#define D_INNER 512
#define NHEADS 8
#define D_XBC 640
#define NPROJ 1160
#define BATCH 64
#define SEQ 250
#define ROWS (BATCH * SEQ) /* 16000 */
#define KIN 240            /* effective K for gemm1: u cols 240..255 are zero pad */
#define KPAD 256           /* K padded for MFMA */
#define NPAD 1216          /* N padded to multiple of 64 */

typedef __bf16 bf16x8 __attribute__((ext_vector_type(8)));
typedef float f32x4 __attribute__((ext_vector_type(4)));

__device__ __forceinline__ float readlane_f(float v, int lane) {
    return __uint_as_float(__builtin_amdgcn_readlane(__float_as_uint(v), lane));
}
__device__ __forceinline__ float silu_f(float x) { return x * (1.f / (1.f + __expf(-x))); }
__device__ __forceinline__ unsigned short bf16_rne(float f) {
    unsigned int u = __float_as_uint(f);
    u += 0x7fff + ((u >> 16) & 1);
    return (unsigned short)(u >> 16);
}

// ---------------------------------------------------------------------------
// Kernel 0: cast x -> A_bf [16000][256] (K zero-padded), W_in -> Bt_bf [1216][256]
// (transposed, so gemm1 stages both operands own-dim-major, k-contiguous)
// ---------------------------------------------------------------------------
__global__ __launch_bounds__(256) void cast_kernel(const float* __restrict__ x,
                                                   const float* __restrict__ Win,
                                                   unsigned short* __restrict__ a_bf,
                                                   unsigned short* __restrict__ bt_bf) {
    int idx = blockIdx.x * 256 + threadIdx.x;
    const int NA = ROWS * KPAD;
    if (idx < NA) {
        int row = idx >> 8, c = idx & 255;
        float v = (c < KIN) ? x[row * KIN + c] : 0.f;
        a_bf[idx] = bf16_rne(v);
    } else if (idx < NA + NPAD * KPAD) {
        int r = idx - NA;
        int n = r >> 8, k = r & 255;
        float v = (n < NPROJ && k < KIN) ? Win[k * NPROJ + n] : 0.f;
        bt_bf[r] = bf16_rne(v);
    }
}

// ---------------------------------------------------------------------------
// Kernel 1: zxbcdt[16000][1160] = A_bf @ Bt_bf^T via 16x16x32 bf16 MFMA.
// Block = 256 thr (4 waves, 2x2), tile 128(M) x 64(N), BK=32, fp32 output.
// ---------------------------------------------------------------------------
#define SA 40  /* padded LDS stride (bf16 elems): 20 words -> spread banks */
__global__ __launch_bounds__(256) void gemm1_mfma(const unsigned short* __restrict__ A,
                                                  const unsigned short* __restrict__ Bt,
                                                  float* __restrict__ C) {
    __shared__ unsigned short As[128 * SA];
    __shared__ unsigned short Bs[64 * SA];
    const int tid = threadIdx.x;
    const int lane = tid & 63, wave = tid >> 6;
    const int wm = wave >> 1, wn = wave & 1;
    const int q = lane >> 4, l15 = lane & 15;
    const int rowBase = blockIdx.y * 128, colBase = blockIdx.x * 64;
    f32x4 acc[4][2] = {};

    const int sr = tid >> 2;           // staging row 0..63
    const int sc = (tid & 3) * 8;      // staging col seg (8 bf16 = 16B)

    for (int k0 = 0; k0 < KPAD; k0 += 32) {
        *(float4*)&As[sr * SA + sc] =
            *(const float4*)&A[(size_t)(rowBase + sr) * KPAD + k0 + sc];
        *(float4*)&As[(sr + 64) * SA + sc] =
            *(const float4*)&A[(size_t)(rowBase + sr + 64) * KPAD + k0 + sc];
        *(float4*)&Bs[sr * SA + sc] =
            *(const float4*)&Bt[(size_t)(colBase + sr) * KPAD + k0 + sc];
        __syncthreads();

        bf16x8 bfr[2];
#pragma unroll
        for (int nt = 0; nt < 2; nt++)
            bfr[nt] = *(const bf16x8*)&Bs[(wn * 32 + nt * 16 + l15) * SA + q * 8];
#pragma unroll
        for (int mt = 0; mt < 4; mt++) {
            bf16x8 afr = *(const bf16x8*)&As[(wm * 64 + mt * 16 + l15) * SA + q * 8];
#pragma unroll
            for (int nt = 0; nt < 2; nt++)
                acc[mt][nt] = __builtin_amdgcn_mfma_f32_16x16x32_bf16(afr, bfr[nt],
                                                                      acc[mt][nt], 0, 0, 0);
        }
        __syncthreads();
    }
#pragma unroll
    for (int mt = 0; mt < 4; mt++) {
        int grow = rowBase + wm * 64 + mt * 16 + q * 4;
#pragma unroll
        for (int nt = 0; nt < 2; nt++) {
            int gcol = colBase + wn * 32 + nt * 16 + l15;
            if (gcol < NPROJ) {
#pragma unroll
                for (int reg = 0; reg < 4; reg++)
                    C[(size_t)(grow + reg) * NPROJ + gcol] = acc[mt][nt][reg];
            }
        }
    }
}

// ---------------------------------------------------------------------------
// Kernel 2: causal depthwise conv4 + bias + SiLU over xBC cols; softplus(dt)
// ---------------------------------------------------------------------------
__global__ __launch_bounds__(256) void conv_kernel(const float* __restrict__ zxbcdt,
                                                   const float* __restrict__ conv_w,
                                                   const float* __restrict__ conv_b,
                                                   const float* __restrict__ dt_bias,
                                                   float* __restrict__ xc,
                                                   float* __restrict__ dtp) {
    const int NCONV = ROWS * D_XBC;
    int idx = blockIdx.x * 256 + threadIdx.x;
    if (idx < NCONV) {
        int row = idx / D_XBC;
        int ch = idx - row * D_XBC;
        int t = row % SEQ;
        float accv = conv_b[ch];
#pragma unroll
        for (int k = 0; k < 4; k++) {
            int tt = t - 3 + k;
            if (tt >= 0)
                accv = fmaf(zxbcdt[(size_t)(row - 3 + k) * NPROJ + D_INNER + ch],
                            conv_w[ch * 4 + k], accv);
        }
        xc[idx] = silu_f(accv);
    } else if (idx < NCONV + ROWS * NHEADS) {
        int r = idx - NCONV;
        int row = r >> 3, h = r & 7;
        float v = zxbcdt[(size_t)row * NPROJ + (D_INNER + D_XBC) + h] + dt_bias[h];
        dtp[r] = (v > 20.f) ? v : __logf(1.f + __expf(v));
    }
}

// ---------------------------------------------------------------------------
// Kernel 3: SSM scan v2. One block (4 waves) per (batch, head); lane = p.
// State dim n split across waves (16 each); prefetched loads; LDS combine.
// ---------------------------------------------------------------------------
__global__ __launch_bounds__(256) void scan_kernel(const float* __restrict__ xc,
                                                   const float* __restrict__ dtp,
                                                   const float* __restrict__ A_log,
                                                   const float* __restrict__ Dvec,
                                                   float* __restrict__ yout) {
    const int bh = blockIdx.x;
    const int b = bh >> 3, h = bh & 7;
    const int tid = threadIdx.x;
    const int lane = tid & 63;
    const int w = tid >> 6;   // wave id 0..3; owns states n0..n0+15
    const int n0 = w * 16;
    const float A = -__expf(A_log[h]);
    const float Dh = Dvec[h];
    float hreg[16];
#pragma unroll
    for (int n = 0; n < 16; n++) hreg[n] = 0.f;
    __shared__ float part[4][64];

    const float* xcb = xc + (size_t)b * SEQ * D_XBC;
    const float* dtb = dtp + b * SEQ * NHEADS + h;
    float* yb = yout + (size_t)b * SEQ * D_INNER + h * HEADDIM + lane;

    float xv = xcb[h * HEADDIM + lane];
    float Bv = xcb[D_INNER + lane];
    float Cv = xcb[D_INNER + D_STATE + lane];
    float dtv = dtb[0];

    for (int t = 0; t < SEQ; t++) {
        int tn = (t + 1 < SEQ) ? (t + 1) : (SEQ - 1);
        const float* rq = xcb + tn * D_XBC;
        float xv_n = rq[h * HEADDIM + lane];
        float Bv_n = rq[D_INNER + lane];
        float Cv_n = rq[D_INNER + D_STATE + lane];
        float dtv_n = dtb[tn * NHEADS];

        float decay = __expf(dtv * A);
        float coef = dtv * xv;
        float acc[4] = {0.f, 0.f, 0.f, 0.f};
#pragma unroll
        for (int n = 0; n < 16; n++) {
            float Bn = readlane_f(Bv, n0 + n);
            float Cn = readlane_f(Cv, n0 + n);
            hreg[n] = fmaf(hreg[n], decay, coef * Bn);
            acc[n & 3] = fmaf(hreg[n], Cn, acc[n & 3]);
        }
        part[w][lane] = (acc[0] + acc[1]) + (acc[2] + acc[3]);
        __syncthreads();
        if (w == 0) {
            float y = (part[0][lane] + part[1][lane]) + (part[2][lane] + part[3][lane]);
            yb[t * D_INNER] = fmaf(Dh, xv, y);
        }
        __syncthreads();
        xv = xv_n; Bv = Bv_n; Cv = Cv_n; dtv = dtv_n;
    }
}

// ---------------------------------------------------------------------------
// Kernel 4: per-row RMS scale of g = y * silu(z). One wave per row.
// ---------------------------------------------------------------------------
__global__ __launch_bounds__(256) void rms_kernel(const float* __restrict__ yout,
                                                  const float* __restrict__ zx,
                                                  float* __restrict__ rms) {
    const int wid = threadIdx.x >> 6, lane = threadIdx.x & 63;
    const int row = blockIdx.x * 4 + wid;
    const float* yr = yout + (size_t)row * D_INNER;
    const float* zr = zx + (size_t)row * NPROJ;
    float s = 0.f;
#pragma unroll
    for (int j = 0; j < 8; j++) {
        int i = j * 64 + lane;
        float g = yr[i] * silu_f(zr[i]);
        s = fmaf(g, g, s);
    }
#pragma unroll
    for (int o = 32; o; o >>= 1) s += __shfl_xor(s, o, 64);
    if (lane == 0) rms[row] = rsqrtf(s * (1.f / 512.f) + 1e-5f);
}

// ---------------------------------------------------------------------------
// Kernel 5: out = selu( (g*rms*norm_w) @ W_out )[:, :240]
// ---------------------------------------------------------------------------
__global__ __launch_bounds__(256) void gemm2_kernel(const float* __restrict__ yout,
                                                    const float* __restrict__ zx,
                                                    const float* __restrict__ rms,
                                                    const float* __restrict__ norm_w,
                                                    const float* __restrict__ Wout,
                                                    float* __restrict__ out) {
    __shared__ float As2[64][17];
    __shared__ float Bs2[16][64];
    const int tid = threadIdx.x;
    const int tx = tid & 15, ty = tid >> 4;
    const int rowBase = blockIdx.y * 64;
    const int colBase = blockIdx.x * 64;
    float acc[4][4] = {};

    for (int k0 = 0; k0 < D_INNER; k0 += 16) {
#pragma unroll
        for (int i = 0; i < 4; i++) {
            int flat = tid + i * 256;
            int ar = flat >> 4, ak = flat & 15;
            int grow = rowBase + ar;
            int kk = k0 + ak;
            float g = yout[(size_t)grow * D_INNER + kk] * silu_f(zx[(size_t)grow * NPROJ + kk]);
            As2[ar][ak] = g * rms[grow] * norm_w[kk];
        }
#pragma unroll
        for (int i = 0; i < 4; i++) {
            int flat = tid + i * 256;
            int bk = flat >> 6, bc = flat & 63;
            Bs2[bk][bc] = Wout[(k0 + bk) * D_MODEL + colBase + bc];
        }
        __syncthreads();
#pragma unroll
        for (int kk = 0; kk < 16; kk++) {
            float a[4], b[4];
#pragma unroll
            for (int i = 0; i < 4; i++) a[i] = As2[ty * 4 + i][kk];
#pragma unroll
            for (int j = 0; j < 4; j++) b[j] = Bs2[kk][tx * 4 + j];
#pragma unroll
            for (int i = 0; i < 4; i++)
#pragma unroll
                for (int j = 0; j < 4; j++) acc[i][j] = fmaf(a[i], b[j], acc[i][j]);
        }
        __syncthreads();
    }
    const float SC = 1.0507009873554805f, AL = 1.6732632423543772f;
#pragma unroll
    for (int i = 0; i < 4; i++) {
        int grow = rowBase + ty * 4 + i;
#pragma unroll
        for (int j = 0; j < 4; j++) {
            int gcol = colBase + tx * 4 + j;
            if (gcol < 240) {
                float v = acc[i][j];
                v = (v > 0.f) ? SC * v : SC * AL * (__expf(v) - 1.f);
                out[(size_t)grow * 240 + gcol] = v;
            }
        }
    }
}

// ---------------------------------------------------------------------------
extern "C" void kernel_launch(void* const* d_in, const int* in_sizes, int n_in,
                              void* d_out, int out_size, void* d_ws, size_t ws_size,
                              hipStream_t stream) {
    const float* x = (const float*)d_in[0];
    const float* W_in = (const float*)d_in[1];
    const float* conv_w = (const float*)d_in[2];
    const float* conv_b = (const float*)d_in[3];
    const float* A_log = (const float*)d_in[4];
    const float* dt_bias = (const float*)d_in[5];
    const float* Dv = (const float*)d_in[6];
    const float* norm_w = (const float*)d_in[7];
    const float* W_out = (const float*)d_in[8];
    float* out = (float*)d_out;

    float* ws = (float*)d_ws;
    float* zxbcdt = ws;                                  // 16000*1160
    float* xc = zxbcdt + (size_t)ROWS * NPROJ;           // 16000*640
    float* dtp = xc + (size_t)ROWS * D_XBC;              // 16000*8
    float* yout = dtp + (size_t)ROWS * NHEADS;           // 16000*512
    float* rms = yout + (size_t)ROWS * D_INNER;          // 16000

    // bf16 staging buffers alias the xc region (dead until conv_kernel runs)
    unsigned short* a_bf = (unsigned short*)xc;          // 16000*256 bf16 (8.2 MB)
    unsigned short* bt_bf = a_bf + (size_t)ROWS * KPAD;  // 1216*256 bf16 (0.6 MB)

    int cast_total = ROWS * KPAD + NPAD * KPAD;
    cast_kernel<<<dim3((cast_total + 255) / 256), 256, 0, stream>>>(x, W_in, a_bf, bt_bf);

    gemm1_mfma<<<dim3(NPAD / 64, ROWS / 128), 256, 0, stream>>>(a_bf, bt_bf, zxbcdt);

    int conv_total = ROWS * D_XBC + ROWS * NHEADS;
    conv_kernel<<<dim3((conv_total + 255) / 256), 256, 0, stream>>>(zxbcdt, conv_w, conv_b,
                                                                    dt_bias, xc, dtp);

    scan_kernel<<<dim3(BATCH * NHEADS), 256, 0, stream>>>(xc, dtp, A_log, Dv, yout);

    rms_kernel<<<dim3(ROWS / 4), 256, 0, stream>>>(yout, zxbcdt, rms);

    gemm2_kernel<<<dim3(4, 250), 256, 0, stream>>>(yout, zxbcdt, rms, norm_w, W_out, out);
}

// Round 4
// 326.093 us; speedup vs baseline: 1.7394x; 1.3197x over previous
//
#include <hip/hip_runtime.h>
#include <cstdint>
#include <cstddef>

#define D_MODEL 256
#define D_STATE 64
#define HEADDIM 64
#define D_INNER 512
#define NHEADS 8
#define D_XBC 640
#define NPROJ 1160
#define BATCH 64
#define SEQ 250
#define ROWS (BATCH * SEQ) /* 16000 */
#define KIN 240            /* effective K for gemm1: u cols 240..255 are zero pad */
#define KPAD 256           /* K padded for MFMA */
#define NPAD 1216          /* N padded to multiple of 64 */

typedef __bf16 bf16x8 __attribute__((ext_vector_type(8)));
typedef float f32x4 __attribute__((ext_vector_type(4)));

__device__ __forceinline__ float readlane_f(float v, int lane) {
    return __uint_as_float(__builtin_amdgcn_readlane(__float_as_uint(v), lane));
}
__device__ __forceinline__ float silu_f(float x) { return x * (1.f / (1.f + __expf(-x))); }
__device__ __forceinline__ unsigned short bf16_rne(float f) {
    unsigned int u = __float_as_uint(f);
    u += 0x7fff + ((u >> 16) & 1);
    return (unsigned short)(u >> 16);
}

// ---------------------------------------------------------------------------
// Kernel 0: cast x -> A_bf [16000][256] (K zero-padded), W_in -> Bt_bf [1216][256]
// ---------------------------------------------------------------------------
__global__ __launch_bounds__(256) void cast_kernel(const float* __restrict__ x,
                                                   const float* __restrict__ Win,
                                                   unsigned short* __restrict__ a_bf,
                                                   unsigned short* __restrict__ bt_bf) {
    int idx = blockIdx.x * 256 + threadIdx.x;
    const int NA = ROWS * KPAD;
    if (idx < NA) {
        int row = idx >> 8, c = idx & 255;
        float v = (c < KIN) ? x[row * KIN + c] : 0.f;
        a_bf[idx] = bf16_rne(v);
    } else if (idx < NA + NPAD * KPAD) {
        int r = idx - NA;
        int n = r >> 8, k = r & 255;
        float v = (n < NPROJ && k < KIN) ? Win[k * NPROJ + n] : 0.f;
        bt_bf[r] = bf16_rne(v);
    }
}

// ---------------------------------------------------------------------------
// Kernel 1: zxbcdt[16000][1160] = A_bf @ Bt_bf^T via 16x16x32 bf16 MFMA.
// ---------------------------------------------------------------------------
#define SA 40
__global__ __launch_bounds__(256) void gemm1_mfma(const unsigned short* __restrict__ A,
                                                  const unsigned short* __restrict__ Bt,
                                                  float* __restrict__ C) {
    __shared__ unsigned short As[128 * SA];
    __shared__ unsigned short Bs[64 * SA];
    const int tid = threadIdx.x;
    const int lane = tid & 63, wave = tid >> 6;
    const int wm = wave >> 1, wn = wave & 1;
    const int q = lane >> 4, l15 = lane & 15;
    const int rowBase = blockIdx.y * 128, colBase = blockIdx.x * 64;
    f32x4 acc[4][2] = {};

    const int sr = tid >> 2;
    const int sc = (tid & 3) * 8;

    for (int k0 = 0; k0 < KPAD; k0 += 32) {
        *(float4*)&As[sr * SA + sc] =
            *(const float4*)&A[(size_t)(rowBase + sr) * KPAD + k0 + sc];
        *(float4*)&As[(sr + 64) * SA + sc] =
            *(const float4*)&A[(size_t)(rowBase + sr + 64) * KPAD + k0 + sc];
        *(float4*)&Bs[sr * SA + sc] =
            *(const float4*)&Bt[(size_t)(colBase + sr) * KPAD + k0 + sc];
        __syncthreads();

        bf16x8 bfr[2];
#pragma unroll
        for (int nt = 0; nt < 2; nt++)
            bfr[nt] = *(const bf16x8*)&Bs[(wn * 32 + nt * 16 + l15) * SA + q * 8];
#pragma unroll
        for (int mt = 0; mt < 4; mt++) {
            bf16x8 afr = *(const bf16x8*)&As[(wm * 64 + mt * 16 + l15) * SA + q * 8];
#pragma unroll
            for (int nt = 0; nt < 2; nt++)
                acc[mt][nt] = __builtin_amdgcn_mfma_f32_16x16x32_bf16(afr, bfr[nt],
                                                                      acc[mt][nt], 0, 0, 0);
        }
        __syncthreads();
    }
#pragma unroll
    for (int mt = 0; mt < 4; mt++) {
        int grow = rowBase + wm * 64 + mt * 16 + q * 4;
#pragma unroll
        for (int nt = 0; nt < 2; nt++) {
            int gcol = colBase + wn * 32 + nt * 16 + l15;
            if (gcol < NPROJ) {
#pragma unroll
                for (int reg = 0; reg < 4; reg++)
                    C[(size_t)(grow + reg) * NPROJ + gcol] = acc[mt][nt][reg];
            }
        }
    }
}

// ---------------------------------------------------------------------------
// Kernel 2: causal depthwise conv4 + bias + SiLU over xBC cols; softplus(dt)
// ---------------------------------------------------------------------------
__global__ __launch_bounds__(256) void conv_kernel(const float* __restrict__ zxbcdt,
                                                   const float* __restrict__ conv_w,
                                                   const float* __restrict__ conv_b,
                                                   const float* __restrict__ dt_bias,
                                                   float* __restrict__ xc,
                                                   float* __restrict__ dtp) {
    const int NCONV = ROWS * D_XBC;
    int idx = blockIdx.x * 256 + threadIdx.x;
    if (idx < NCONV) {
        int row = idx / D_XBC;
        int ch = idx - row * D_XBC;
        int t = row % SEQ;
        float accv = conv_b[ch];
#pragma unroll
        for (int k = 0; k < 4; k++) {
            int tt = t - 3 + k;
            if (tt >= 0)
                accv = fmaf(zxbcdt[(size_t)(row - 3 + k) * NPROJ + D_INNER + ch],
                            conv_w[ch * 4 + k], accv);
        }
        xc[idx] = silu_f(accv);
    } else if (idx < NCONV + ROWS * NHEADS) {
        int r = idx - NCONV;
        int row = r >> 3, h = r & 7;
        float v = zxbcdt[(size_t)row * NPROJ + (D_INNER + D_XBC) + h] + dt_bias[h];
        dtp[r] = (v > 20.f) ? v : __logf(1.f + __expf(v));
    }
}

// ---------------------------------------------------------------------------
// Kernel 3: chunked SSD scan via bf16 MFMA. One block (4 waves) per (b,h);
// 4 chunks of Q=64 processed sequentially with fp32 h-carry in registers.
//   G = C.B^T; P = G*exp(cs_t-cs_s)*[s<=t]; Yintra = P.(dt*x);
//   ST[p][n] = (dt*x)^T.(w_s*B); Yinter = alpha_t*(C.h); h' = lam*h + ST.
// ---------------------------------------------------------------------------
#define LSTR 72  /* LDS row stride (bf16): 144B, 16B-aligned, bank-spread */
__global__ __launch_bounds__(256) void scan_mfma(const float* __restrict__ xc,
                                                 const float* __restrict__ dtp,
                                                 const float* __restrict__ A_log,
                                                 const float* __restrict__ Dvec,
                                                 float* __restrict__ yout) {
    __shared__ unsigned short C_l[64 * LSTR];
    __shared__ unsigned short B_l[64 * LSTR];
    __shared__ unsigned short XT_l[64 * LSTR];   // (dt*x)^T : row p, col s
    __shared__ unsigned short BwT_l[64 * LSTR];  // (w_s*B)^T: row n, col s
    __shared__ unsigned short P_l[64 * LSTR];    // row t, col s
    __shared__ unsigned short h_l[64 * LSTR];    // h^T bf16: row p, col n
    __shared__ float cs_s[64], dts_s[64], ws_s[64];

    const int bh = blockIdx.x;
    const int b = bh >> 3, h = bh & 7;
    const int tid = threadIdx.x;
    const int lane = tid & 63, w = tid >> 6;
    const int q = lane >> 4, l15 = lane & 15;
    const float A = -__expf(A_log[h]);
    const float Dh = Dvec[h];
    const float* xcb = xc + (size_t)b * SEQ * D_XBC;

    f32x4 hreg[4] = {};  // h^T strip: rows p = w*16+q*4+r, cols n = nt*16+l15

    for (int i = tid; i < 64 * LSTR; i += 256) h_l[i] = 0;
    __syncthreads();

    for (int c = 0; c < 4; c++) {
        const int t0 = c * 64;
        __syncthreads();  // B1: prior chunk's LDS reads complete

        // ---- stage C_l, B_l (row t/s, col n contiguous) ----
        {
            int r = tid >> 2, c0 = (tid & 3) * 16;
            bool valid = (t0 + r) < SEQ;
            const float* rowp = xcb + (size_t)(t0 + r) * D_XBC;
#pragma unroll
            for (int i = 0; i < 4; i++) {
                float4 vc = {0.f, 0.f, 0.f, 0.f}, vb = {0.f, 0.f, 0.f, 0.f};
                if (valid) {
                    vc = *(const float4*)&rowp[D_INNER + D_STATE + c0 + 4 * i];
                    vb = *(const float4*)&rowp[D_INNER + c0 + 4 * i];
                }
                ushort4 pc, pb;
                pc.x = bf16_rne(vc.x); pc.y = bf16_rne(vc.y);
                pc.z = bf16_rne(vc.z); pc.w = bf16_rne(vc.w);
                pb.x = bf16_rne(vb.x); pb.y = bf16_rne(vb.y);
                pb.z = bf16_rne(vb.z); pb.w = bf16_rne(vb.w);
                *(ushort4*)&C_l[r * LSTR + c0 + 4 * i] = pc;
                *(ushort4*)&B_l[r * LSTR + c0 + 4 * i] = pb;
            }
        }
        // ---- wave 0: dt, cumsum(dt*A), weights ----
        if (w == 0) {
            int t = lane;
            bool valid = (t0 + t) < SEQ;
            float dtv = valid ? dtp[(size_t)(b * SEQ + t0 + t) * NHEADS + h] : 0.f;
            float csv = dtv * A;
#pragma unroll
            for (int o = 1; o < 64; o <<= 1) {
                float u = __shfl_up(csv, o, 64);
                if (lane >= o) csv += u;
            }
            float tot = readlane_f(csv, 63);
            cs_s[t] = csv;
            dts_s[t] = dtv;
            ws_s[t] = __expf(tot - csv);
        }
        __syncthreads();  // B2: cs/dts/ws + C/B staged

        // ---- stage XT_l (dt*x transposed), BwT_l (w_s*B transposed) ----
        {
            int p = tid >> 2, s0 = (tid & 3) * 16;
#pragma unroll
            for (int i = 0; i < 4; i++) {
                ushort4 px, pbw;
                unsigned short* xp = (unsigned short*)&px;
                unsigned short* bp = (unsigned short*)&pbw;
#pragma unroll
                for (int j = 0; j < 4; j++) {
                    int s = s0 + 4 * i + j;
                    bool valid = (t0 + s) < SEQ;
                    float xv = 0.f, bv = 0.f;
                    if (valid) {
                        const float* rowp = xcb + (size_t)(t0 + s) * D_XBC;
                        xv = rowp[h * HEADDIM + p] * dts_s[s];
                        bv = rowp[D_INNER + p] * ws_s[s];
                    }
                    xp[j] = bf16_rne(xv);
                    bp[j] = bf16_rne(bv);
                }
                *(ushort4*)&XT_l[p * LSTR + s0 + 4 * i] = px;
                *(ushort4*)&BwT_l[p * LSTR + s0 + 4 * i] = pbw;
            }
        }
        __syncthreads();  // B3: all operands staged

        // ---- MFMA: G = C.B^T and Inter = C.h ----
        f32x4 g[4] = {}, in[4] = {};
#pragma unroll
        for (int k0 = 0; k0 < 64; k0 += 32) {
            bf16x8 ca = *(const bf16x8*)&C_l[(w * 16 + l15) * LSTR + k0 + q * 8];
#pragma unroll
            for (int nt = 0; nt < 4; nt++) {
                bf16x8 bb = *(const bf16x8*)&B_l[(nt * 16 + l15) * LSTR + k0 + q * 8];
                g[nt] = __builtin_amdgcn_mfma_f32_16x16x32_bf16(ca, bb, g[nt], 0, 0, 0);
                bf16x8 hb = *(const bf16x8*)&h_l[(nt * 16 + l15) * LSTR + k0 + q * 8];
                in[nt] = __builtin_amdgcn_mfma_f32_16x16x32_bf16(ca, hb, in[nt], 0, 0, 0);
            }
        }
        // ---- P epilogue: mask + decay, pack pairs, write P_l ----
#pragma unroll
        for (int nt = 0; nt < 4; nt++) {
#pragma unroll
            for (int r = 0; r < 4; r++) {
                int t = w * 16 + q * 4 + r;
                int s = nt * 16 + l15;
                float pv = (s <= t) ? g[nt][r] * __expf(cs_s[t] - cs_s[s]) : 0.f;
                unsigned int u = bf16_rne(pv);
                unsigned int partner = (unsigned int)__shfl_xor((int)u, 1, 64);
                if ((l15 & 1) == 0)
                    *(unsigned int*)&P_l[t * LSTR + nt * 16 + l15] = u | (partner << 16);
            }
        }
        __syncthreads();  // B4: P ready; Yinter reads of h_l done

        // ---- Y = Yintra + alpha_t*Inter ----
        f32x4 y[4];
#pragma unroll
        for (int nt = 0; nt < 4; nt++)
#pragma unroll
            for (int r = 0; r < 4; r++) {
                int t = w * 16 + q * 4 + r;
                y[nt][r] = in[nt][r] * __expf(cs_s[t]);
            }
#pragma unroll
        for (int k0 = 0; k0 < 64; k0 += 32) {
            bf16x8 pa = *(const bf16x8*)&P_l[(w * 16 + l15) * LSTR + k0 + q * 8];
#pragma unroll
            for (int nt = 0; nt < 4; nt++) {
                bf16x8 xb = *(const bf16x8*)&XT_l[(nt * 16 + l15) * LSTR + k0 + q * 8];
                y[nt] = __builtin_amdgcn_mfma_f32_16x16x32_bf16(pa, xb, y[nt], 0, 0, 0);
            }
        }
        // ---- ST[p][n] = (dt*x)^T.(w*B) and h carry ----
        f32x4 st[4] = {};
#pragma unroll
        for (int k0 = 0; k0 < 64; k0 += 32) {
            bf16x8 xa = *(const bf16x8*)&XT_l[(w * 16 + l15) * LSTR + k0 + q * 8];
#pragma unroll
            for (int nt = 0; nt < 4; nt++) {
                bf16x8 bwb = *(const bf16x8*)&BwT_l[(nt * 16 + l15) * LSTR + k0 + q * 8];
                st[nt] = __builtin_amdgcn_mfma_f32_16x16x32_bf16(xa, bwb, st[nt], 0, 0, 0);
            }
        }
        float lam = __expf(cs_s[63]);
#pragma unroll
        for (int nt = 0; nt < 4; nt++)
#pragma unroll
            for (int r = 0; r < 4; r++) {
                hreg[nt][r] = fmaf(hreg[nt][r], lam, st[nt][r]);
                unsigned int u = bf16_rne(hreg[nt][r]);
                unsigned int partner = (unsigned int)__shfl_xor((int)u, 1, 64);
                if ((l15 & 1) == 0)
                    *(unsigned int*)&h_l[(w * 16 + q * 4 + r) * LSTR + nt * 16 + l15] =
                        u | (partner << 16);
            }
        // ---- y epilogue: + D*x, store ----
#pragma unroll
        for (int nt = 0; nt < 4; nt++)
#pragma unroll
            for (int r = 0; r < 4; r++) {
                int t = w * 16 + q * 4 + r;
                if (t0 + t < SEQ) {
                    int p = nt * 16 + l15;
                    float xv = xcb[(size_t)(t0 + t) * D_XBC + h * HEADDIM + p];
                    yout[(size_t)(b * SEQ + t0 + t) * D_INNER + h * HEADDIM + p] =
                        fmaf(Dh, xv, y[nt][r]);
                }
            }
    }
}

// ---------------------------------------------------------------------------
// Kernel 4: per-row RMS scale of g = y * silu(z). One wave per row.
// ---------------------------------------------------------------------------
__global__ __launch_bounds__(256) void rms_kernel(const float* __restrict__ yout,
                                                  const float* __restrict__ zx,
                                                  float* __restrict__ rms) {
    const int wid = threadIdx.x >> 6, lane = threadIdx.x & 63;
    const int row = blockIdx.x * 4 + wid;
    const float* yr = yout + (size_t)row * D_INNER;
    const float* zr = zx + (size_t)row * NPROJ;
    float s = 0.f;
#pragma unroll
    for (int j = 0; j < 8; j++) {
        int i = j * 64 + lane;
        float g = yr[i] * silu_f(zr[i]);
        s = fmaf(g, g, s);
    }
#pragma unroll
    for (int o = 32; o; o >>= 1) s += __shfl_xor(s, o, 64);
    if (lane == 0) rms[row] = rsqrtf(s * (1.f / 512.f) + 1e-5f);
}

// ---------------------------------------------------------------------------
// Kernel 5: out = selu( (g*rms*norm_w) @ W_out )[:, :240]
// ---------------------------------------------------------------------------
__global__ __launch_bounds__(256) void gemm2_kernel(const float* __restrict__ yout,
                                                    const float* __restrict__ zx,
                                                    const float* __restrict__ rms,
                                                    const float* __restrict__ norm_w,
                                                    const float* __restrict__ Wout,
                                                    float* __restrict__ out) {
    __shared__ float As2[64][17];
    __shared__ float Bs2[16][64];
    const int tid = threadIdx.x;
    const int tx = tid & 15, ty = tid >> 4;
    const int rowBase = blockIdx.y * 64;
    const int colBase = blockIdx.x * 64;
    float acc[4][4] = {};

    for (int k0 = 0; k0 < D_INNER; k0 += 16) {
#pragma unroll
        for (int i = 0; i < 4; i++) {
            int flat = tid + i * 256;
            int ar = flat >> 4, ak = flat & 15;
            int grow = rowBase + ar;
            int kk = k0 + ak;
            float g = yout[(size_t)grow * D_INNER + kk] * silu_f(zx[(size_t)grow * NPROJ + kk]);
            As2[ar][ak] = g * rms[grow] * norm_w[kk];
        }
#pragma unroll
        for (int i = 0; i < 4; i++) {
            int flat = tid + i * 256;
            int bk = flat >> 6, bc = flat & 63;
            Bs2[bk][bc] = Wout[(k0 + bk) * D_MODEL + colBase + bc];
        }
        __syncthreads();
#pragma unroll
        for (int kk = 0; kk < 16; kk++) {
            float a[4], b[4];
#pragma unroll
            for (int i = 0; i < 4; i++) a[i] = As2[ty * 4 + i][kk];
#pragma unroll
            for (int j = 0; j < 4; j++) b[j] = Bs2[kk][tx * 4 + j];
#pragma unroll
            for (int i = 0; i < 4; i++)
#pragma unroll
                for (int j = 0; j < 4; j++) acc[i][j] = fmaf(a[i], b[j], acc[i][j]);
        }
        __syncthreads();
    }
    const float SC = 1.0507009873554805f, AL = 1.6732632423543772f;
#pragma unroll
    for (int i = 0; i < 4; i++) {
        int grow = rowBase + ty * 4 + i;
#pragma unroll
        for (int j = 0; j < 4; j++) {
            int gcol = colBase + tx * 4 + j;
            if (gcol < 240) {
                float v = acc[i][j];
                v = (v > 0.f) ? SC * v : SC * AL * (__expf(v) - 1.f);
                out[(size_t)grow * 240 + gcol] = v;
            }
        }
    }
}

// ---------------------------------------------------------------------------
extern "C" void kernel_launch(void* const* d_in, const int* in_sizes, int n_in,
                              void* d_out, int out_size, void* d_ws, size_t ws_size,
                              hipStream_t stream) {
    const float* x = (const float*)d_in[0];
    const float* W_in = (const float*)d_in[1];
    const float* conv_w = (const float*)d_in[2];
    const float* conv_b = (const float*)d_in[3];
    const float* A_log = (const float*)d_in[4];
    const float* dt_bias = (const float*)d_in[5];
    const float* Dv = (const float*)d_in[6];
    const float* norm_w = (const float*)d_in[7];
    const float* W_out = (const float*)d_in[8];
    float* out = (float*)d_out;

    float* ws = (float*)d_ws;
    float* zxbcdt = ws;                                  // 16000*1160
    float* xc = zxbcdt + (size_t)ROWS * NPROJ;           // 16000*640
    float* dtp = xc + (size_t)ROWS * D_XBC;              // 16000*8
    float* yout = dtp + (size_t)ROWS * NHEADS;           // 16000*512
    float* rms = yout + (size_t)ROWS * D_INNER;          // 16000

    // bf16 staging buffers alias the xc region (dead until conv_kernel runs)
    unsigned short* a_bf = (unsigned short*)xc;          // 16000*256 bf16
    unsigned short* bt_bf = a_bf + (size_t)ROWS * KPAD;  // 1216*256 bf16

    int cast_total = ROWS * KPAD + NPAD * KPAD;
    cast_kernel<<<dim3((cast_total + 255) / 256), 256, 0, stream>>>(x, W_in, a_bf, bt_bf);

    gemm1_mfma<<<dim3(NPAD / 64, ROWS / 128), 256, 0, stream>>>(a_bf, bt_bf, zxbcdt);

    int conv_total = ROWS * D_XBC + ROWS * NHEADS;
    conv_kernel<<<dim3((conv_total + 255) / 256), 256, 0, stream>>>(zxbcdt, conv_w, conv_b,
                                                                    dt_bias, xc, dtp);

    scan_mfma<<<dim3(BATCH * NHEADS), 256, 0, stream>>>(xc, dtp, A_log, Dv, yout);

    rms_kernel<<<dim3(ROWS / 4), 256, 0, stream>>>(yout, zxbcdt, rms);

    gemm2_kernel<<<dim3(4, 250), 256, 0, stream>>>(yout, zxbcdt, rms, norm_w, W_out, out);
}

// Round 5
// 259.431 us; speedup vs baseline: 2.1864x; 1.2570x over previous
//
#include <hip/hip_runtime.h>
#include <cstdint>
#include <cstddef>

#define D_MODEL 256
#define D_STATE 64
#define HEADDIM 64
#define D_INNER 512
#define NHEADS 8
#define D_XBC 640
#define NPROJ 1160
#define BATCH 64
#define SEQ 250
#define ROWS (BATCH * SEQ) /* 16000 */
#define KIN 240            /* effective K for gemm1: u cols 240..255 are zero pad */
#define KPAD 256           /* K padded for MFMA */
#define NPAD 1216          /* N padded to multiple of 64 */

typedef __bf16 bf16x8 __attribute__((ext_vector_type(8)));
typedef float f32x4 __attribute__((ext_vector_type(4)));

__device__ __forceinline__ float readlane_f(float v, int lane) {
    return __uint_as_float(__builtin_amdgcn_readlane(__float_as_uint(v), lane));
}
__device__ __forceinline__ float silu_f(float x) { return x * (1.f / (1.f + __expf(-x))); }
__device__ __forceinline__ unsigned short bf16_rne(float f) {
    unsigned int u = __float_as_uint(f);
    u += 0x7fff + ((u >> 16) & 1);
    return (unsigned short)(u >> 16);
}
__device__ __forceinline__ unsigned int pack2(float a, float b) {
    return (unsigned int)bf16_rne(a) | ((unsigned int)bf16_rne(b) << 16);
}

// ---------------------------------------------------------------------------
// Kernel 0: cast x -> A_bf [16000][256] (K zero-padded), W_in -> Bt_bf [1216][256]
// ---------------------------------------------------------------------------
__global__ __launch_bounds__(256) void cast_kernel(const float* __restrict__ x,
                                                   const float* __restrict__ Win,
                                                   unsigned short* __restrict__ a_bf,
                                                   unsigned short* __restrict__ bt_bf) {
    int idx = blockIdx.x * 256 + threadIdx.x;
    const int NA = ROWS * KPAD;
    if (idx < NA) {
        int row = idx >> 8, c = idx & 255;
        float v = (c < KIN) ? x[row * KIN + c] : 0.f;
        a_bf[idx] = bf16_rne(v);
    } else if (idx < NA + NPAD * KPAD) {
        int r = idx - NA;
        int n = r >> 8, k = r & 255;
        float v = (n < NPROJ && k < KIN) ? Win[k * NPROJ + n] : 0.f;
        bt_bf[r] = bf16_rne(v);
    }
}

// ---------------------------------------------------------------------------
// Kernel 1: zxbcdt[16000][1160] = A_bf @ Bt_bf^T via 16x16x32 bf16 MFMA.
// ---------------------------------------------------------------------------
#define SA 40
__global__ __launch_bounds__(256) void gemm1_mfma(const unsigned short* __restrict__ A,
                                                  const unsigned short* __restrict__ Bt,
                                                  float* __restrict__ C) {
    __shared__ unsigned short As[128 * SA];
    __shared__ unsigned short Bs[64 * SA];
    const int tid = threadIdx.x;
    const int lane = tid & 63, wave = tid >> 6;
    const int wm = wave >> 1, wn = wave & 1;
    const int q = lane >> 4, l15 = lane & 15;
    const int rowBase = blockIdx.y * 128, colBase = blockIdx.x * 64;
    f32x4 acc[4][2] = {};

    const int sr = tid >> 2;
    const int sc = (tid & 3) * 8;

    for (int k0 = 0; k0 < KPAD; k0 += 32) {
        *(float4*)&As[sr * SA + sc] =
            *(const float4*)&A[(size_t)(rowBase + sr) * KPAD + k0 + sc];
        *(float4*)&As[(sr + 64) * SA + sc] =
            *(const float4*)&A[(size_t)(rowBase + sr + 64) * KPAD + k0 + sc];
        *(float4*)&Bs[sr * SA + sc] =
            *(const float4*)&Bt[(size_t)(colBase + sr) * KPAD + k0 + sc];
        __syncthreads();

        bf16x8 bfr[2];
#pragma unroll
        for (int nt = 0; nt < 2; nt++)
            bfr[nt] = *(const bf16x8*)&Bs[(wn * 32 + nt * 16 + l15) * SA + q * 8];
#pragma unroll
        for (int mt = 0; mt < 4; mt++) {
            bf16x8 afr = *(const bf16x8*)&As[(wm * 64 + mt * 16 + l15) * SA + q * 8];
#pragma unroll
            for (int nt = 0; nt < 2; nt++)
                acc[mt][nt] = __builtin_amdgcn_mfma_f32_16x16x32_bf16(afr, bfr[nt],
                                                                      acc[mt][nt], 0, 0, 0);
        }
        __syncthreads();
    }
#pragma unroll
    for (int mt = 0; mt < 4; mt++) {
        int grow = rowBase + wm * 64 + mt * 16 + q * 4;
#pragma unroll
        for (int nt = 0; nt < 2; nt++) {
            int gcol = colBase + wn * 32 + nt * 16 + l15;
            if (gcol < NPROJ) {
#pragma unroll
                for (int reg = 0; reg < 4; reg++)
                    C[(size_t)(grow + reg) * NPROJ + gcol] = acc[mt][nt][reg];
            }
        }
    }
}

// ---------------------------------------------------------------------------
// Kernel 2: causal depthwise conv4 + bias + SiLU over xBC cols; softplus(dt)
// ---------------------------------------------------------------------------
__global__ __launch_bounds__(256) void conv_kernel(const float* __restrict__ zxbcdt,
                                                   const float* __restrict__ conv_w,
                                                   const float* __restrict__ conv_b,
                                                   const float* __restrict__ dt_bias,
                                                   float* __restrict__ xc,
                                                   float* __restrict__ dtp) {
    const int NCONV = ROWS * D_XBC;
    int idx = blockIdx.x * 256 + threadIdx.x;
    if (idx < NCONV) {
        int row = idx / D_XBC;
        int ch = idx - row * D_XBC;
        int t = row % SEQ;
        float accv = conv_b[ch];
#pragma unroll
        for (int k = 0; k < 4; k++) {
            int tt = t - 3 + k;
            if (tt >= 0)
                accv = fmaf(zxbcdt[(size_t)(row - 3 + k) * NPROJ + D_INNER + ch],
                            conv_w[ch * 4 + k], accv);
        }
        xc[idx] = silu_f(accv);
    } else if (idx < NCONV + ROWS * NHEADS) {
        int r = idx - NCONV;
        int row = r >> 3, h = r & 7;
        float v = zxbcdt[(size_t)row * NPROJ + (D_INNER + D_XBC) + h] + dt_bias[h];
        dtp[r] = (v > 20.f) ? v : __logf(1.f + __expf(v));
    }
}

// ---------------------------------------------------------------------------
// Kernel 3: chunked SSD scan via bf16 MFMA. One block (4 waves) per (b,h).
// ---------------------------------------------------------------------------
#define LSTR 72
__global__ __launch_bounds__(256) void scan_mfma(const float* __restrict__ xc,
                                                 const float* __restrict__ dtp,
                                                 const float* __restrict__ A_log,
                                                 const float* __restrict__ Dvec,
                                                 float* __restrict__ yout) {
    __shared__ unsigned short C_l[64 * LSTR];
    __shared__ unsigned short B_l[64 * LSTR];
    __shared__ unsigned short XT_l[64 * LSTR];
    __shared__ unsigned short BwT_l[64 * LSTR];
    __shared__ unsigned short P_l[64 * LSTR];
    __shared__ unsigned short h_l[64 * LSTR];
    __shared__ float cs_s[64], dts_s[64], ws_s[64];

    const int bh = blockIdx.x;
    const int b = bh >> 3, h = bh & 7;
    const int tid = threadIdx.x;
    const int lane = tid & 63, w = tid >> 6;
    const int q = lane >> 4, l15 = lane & 15;
    const float A = -__expf(A_log[h]);
    const float Dh = Dvec[h];
    const float* xcb = xc + (size_t)b * SEQ * D_XBC;

    f32x4 hreg[4] = {};

    for (int i = tid; i < 64 * LSTR; i += 256) h_l[i] = 0;
    __syncthreads();

    for (int c = 0; c < 4; c++) {
        const int t0 = c * 64;
        __syncthreads();

        {
            int r = tid >> 2, c0 = (tid & 3) * 16;
            bool valid = (t0 + r) < SEQ;
            const float* rowp = xcb + (size_t)(t0 + r) * D_XBC;
#pragma unroll
            for (int i = 0; i < 4; i++) {
                float4 vc = {0.f, 0.f, 0.f, 0.f}, vb = {0.f, 0.f, 0.f, 0.f};
                if (valid) {
                    vc = *(const float4*)&rowp[D_INNER + D_STATE + c0 + 4 * i];
                    vb = *(const float4*)&rowp[D_INNER + c0 + 4 * i];
                }
                ushort4 pc, pb;
                pc.x = bf16_rne(vc.x); pc.y = bf16_rne(vc.y);
                pc.z = bf16_rne(vc.z); pc.w = bf16_rne(vc.w);
                pb.x = bf16_rne(vb.x); pb.y = bf16_rne(vb.y);
                pb.z = bf16_rne(vb.z); pb.w = bf16_rne(vb.w);
                *(ushort4*)&C_l[r * LSTR + c0 + 4 * i] = pc;
                *(ushort4*)&B_l[r * LSTR + c0 + 4 * i] = pb;
            }
        }
        if (w == 0) {
            int t = lane;
            bool valid = (t0 + t) < SEQ;
            float dtv = valid ? dtp[(size_t)(b * SEQ + t0 + t) * NHEADS + h] : 0.f;
            float csv = dtv * A;
#pragma unroll
            for (int o = 1; o < 64; o <<= 1) {
                float u = __shfl_up(csv, o, 64);
                if (lane >= o) csv += u;
            }
            float tot = readlane_f(csv, 63);
            cs_s[t] = csv;
            dts_s[t] = dtv;
            ws_s[t] = __expf(tot - csv);
        }
        __syncthreads();

        {
            int p = tid >> 2, s0 = (tid & 3) * 16;
#pragma unroll
            for (int i = 0; i < 4; i++) {
                ushort4 px, pbw;
                unsigned short* xp = (unsigned short*)&px;
                unsigned short* bp = (unsigned short*)&pbw;
#pragma unroll
                for (int j = 0; j < 4; j++) {
                    int s = s0 + 4 * i + j;
                    bool valid = (t0 + s) < SEQ;
                    float xv = 0.f, bv = 0.f;
                    if (valid) {
                        const float* rowp = xcb + (size_t)(t0 + s) * D_XBC;
                        xv = rowp[h * HEADDIM + p] * dts_s[s];
                        bv = rowp[D_INNER + p] * ws_s[s];
                    }
                    xp[j] = bf16_rne(xv);
                    bp[j] = bf16_rne(bv);
                }
                *(ushort4*)&XT_l[p * LSTR + s0 + 4 * i] = px;
                *(ushort4*)&BwT_l[p * LSTR + s0 + 4 * i] = pbw;
            }
        }
        __syncthreads();

        f32x4 g[4] = {}, in[4] = {};
#pragma unroll
        for (int k0 = 0; k0 < 64; k0 += 32) {
            bf16x8 ca = *(const bf16x8*)&C_l[(w * 16 + l15) * LSTR + k0 + q * 8];
#pragma unroll
            for (int nt = 0; nt < 4; nt++) {
                bf16x8 bb = *(const bf16x8*)&B_l[(nt * 16 + l15) * LSTR + k0 + q * 8];
                g[nt] = __builtin_amdgcn_mfma_f32_16x16x32_bf16(ca, bb, g[nt], 0, 0, 0);
                bf16x8 hb = *(const bf16x8*)&h_l[(nt * 16 + l15) * LSTR + k0 + q * 8];
                in[nt] = __builtin_amdgcn_mfma_f32_16x16x32_bf16(ca, hb, in[nt], 0, 0, 0);
            }
        }
#pragma unroll
        for (int nt = 0; nt < 4; nt++) {
#pragma unroll
            for (int r = 0; r < 4; r++) {
                int t = w * 16 + q * 4 + r;
                int s = nt * 16 + l15;
                float pv = (s <= t) ? g[nt][r] * __expf(cs_s[t] - cs_s[s]) : 0.f;
                unsigned int u = bf16_rne(pv);
                unsigned int partner = (unsigned int)__shfl_xor((int)u, 1, 64);
                if ((l15 & 1) == 0)
                    *(unsigned int*)&P_l[t * LSTR + nt * 16 + l15] = u | (partner << 16);
            }
        }
        __syncthreads();

        f32x4 y[4];
#pragma unroll
        for (int nt = 0; nt < 4; nt++)
#pragma unroll
            for (int r = 0; r < 4; r++) {
                int t = w * 16 + q * 4 + r;
                y[nt][r] = in[nt][r] * __expf(cs_s[t]);
            }
#pragma unroll
        for (int k0 = 0; k0 < 64; k0 += 32) {
            bf16x8 pa = *(const bf16x8*)&P_l[(w * 16 + l15) * LSTR + k0 + q * 8];
#pragma unroll
            for (int nt = 0; nt < 4; nt++) {
                bf16x8 xb = *(const bf16x8*)&XT_l[(nt * 16 + l15) * LSTR + k0 + q * 8];
                y[nt] = __builtin_amdgcn_mfma_f32_16x16x32_bf16(pa, xb, y[nt], 0, 0, 0);
            }
        }
        f32x4 st[4] = {};
#pragma unroll
        for (int k0 = 0; k0 < 64; k0 += 32) {
            bf16x8 xa = *(const bf16x8*)&XT_l[(w * 16 + l15) * LSTR + k0 + q * 8];
#pragma unroll
            for (int nt = 0; nt < 4; nt++) {
                bf16x8 bwb = *(const bf16x8*)&BwT_l[(nt * 16 + l15) * LSTR + k0 + q * 8];
                st[nt] = __builtin_amdgcn_mfma_f32_16x16x32_bf16(xa, bwb, st[nt], 0, 0, 0);
            }
        }
        float lam = __expf(cs_s[63]);
#pragma unroll
        for (int nt = 0; nt < 4; nt++)
#pragma unroll
            for (int r = 0; r < 4; r++) {
                hreg[nt][r] = fmaf(hreg[nt][r], lam, st[nt][r]);
                unsigned int u = bf16_rne(hreg[nt][r]);
                unsigned int partner = (unsigned int)__shfl_xor((int)u, 1, 64);
                if ((l15 & 1) == 0)
                    *(unsigned int*)&h_l[(w * 16 + q * 4 + r) * LSTR + nt * 16 + l15] =
                        u | (partner << 16);
            }
#pragma unroll
        for (int nt = 0; nt < 4; nt++)
#pragma unroll
            for (int r = 0; r < 4; r++) {
                int t = w * 16 + q * 4 + r;
                if (t0 + t < SEQ) {
                    int p = nt * 16 + l15;
                    float xv = xcb[(size_t)(t0 + t) * D_XBC + h * HEADDIM + p];
                    yout[(size_t)(b * SEQ + t0 + t) * D_INNER + h * HEADDIM + p] =
                        fmaf(Dh, xv, y[nt][r]);
                }
            }
    }
}

// ---------------------------------------------------------------------------
// Kernel 4: wcast — W_out[512][256] -> wt_bf[256][512] (transposed bf16)
// ---------------------------------------------------------------------------
__global__ __launch_bounds__(256) void wcast_kernel(const float* __restrict__ Wout,
                                                    unsigned short* __restrict__ wt_bf) {
    int idx = blockIdx.x * 256 + threadIdx.x;  // total 512*256
    int n = idx & 255, k = idx >> 8;
    wt_bf[n * D_INNER + k] = bf16_rne(Wout[k * D_MODEL + n]);
}

// ---------------------------------------------------------------------------
// Kernel 5: gate — g = y*silu(z); row rms; g_bf = bf16(g*rms*norm_w).
// One wave per row; lane owns 8 consecutive cols.
// ---------------------------------------------------------------------------
__global__ __launch_bounds__(256) void gate_kernel(const float* __restrict__ yout,
                                                   const float* __restrict__ zx,
                                                   const float* __restrict__ norm_w,
                                                   unsigned short* __restrict__ g_bf) {
    const int wid = threadIdx.x >> 6, lane = threadIdx.x & 63;
    const int row = blockIdx.x * 4 + wid;
    const float* yr = yout + (size_t)row * D_INNER;
    const float* zr = zx + (size_t)row * NPROJ;
    const int c0 = lane * 8;
    float4 y0 = *(const float4*)&yr[c0], y1 = *(const float4*)&yr[c0 + 4];
    float4 z0 = *(const float4*)&zr[c0], z1 = *(const float4*)&zr[c0 + 4];
    float g[8];
    g[0] = y0.x * silu_f(z0.x); g[1] = y0.y * silu_f(z0.y);
    g[2] = y0.z * silu_f(z0.z); g[3] = y0.w * silu_f(z0.w);
    g[4] = y1.x * silu_f(z1.x); g[5] = y1.y * silu_f(z1.y);
    g[6] = y1.z * silu_f(z1.z); g[7] = y1.w * silu_f(z1.w);
    float s = 0.f;
#pragma unroll
    for (int i = 0; i < 8; i++) s = fmaf(g[i], g[i], s);
#pragma unroll
    for (int o = 32; o; o >>= 1) s += __shfl_xor(s, o, 64);
    float rms = rsqrtf(s * (1.f / 512.f) + 1e-5f);
    float4 w0 = *(const float4*)&norm_w[c0], w1 = *(const float4*)&norm_w[c0 + 4];
    uint4 pk;
    pk.x = pack2(g[0] * rms * w0.x, g[1] * rms * w0.y);
    pk.y = pack2(g[2] * rms * w0.z, g[3] * rms * w0.w);
    pk.z = pack2(g[4] * rms * w1.x, g[5] * rms * w1.y);
    pk.w = pack2(g[6] * rms * w1.z, g[7] * rms * w1.w);
    *(uint4*)&g_bf[(size_t)row * D_INNER + c0] = pk;
}

// ---------------------------------------------------------------------------
// Kernel 6: out = selu( g_bf @ wt_bf^T )[:, :240] via bf16 MFMA. K=512.
// ---------------------------------------------------------------------------
__global__ __launch_bounds__(256) void gemm2_mfma(const unsigned short* __restrict__ A,
                                                  const unsigned short* __restrict__ Bt,
                                                  float* __restrict__ out) {
    __shared__ unsigned short As[128 * SA];
    __shared__ unsigned short Bs[64 * SA];
    const int tid = threadIdx.x;
    const int lane = tid & 63, wave = tid >> 6;
    const int wm = wave >> 1, wn = wave & 1;
    const int q = lane >> 4, l15 = lane & 15;
    const int rowBase = blockIdx.y * 128, colBase = blockIdx.x * 64;
    f32x4 acc[4][2] = {};

    const int sr = tid >> 2;
    const int sc = (tid & 3) * 8;

    for (int k0 = 0; k0 < D_INNER; k0 += 32) {
        *(float4*)&As[sr * SA + sc] =
            *(const float4*)&A[(size_t)(rowBase + sr) * D_INNER + k0 + sc];
        *(float4*)&As[(sr + 64) * SA + sc] =
            *(const float4*)&A[(size_t)(rowBase + sr + 64) * D_INNER + k0 + sc];
        *(float4*)&Bs[sr * SA + sc] =
            *(const float4*)&Bt[(size_t)(colBase + sr) * D_INNER + k0 + sc];
        __syncthreads();

        bf16x8 bfr[2];
#pragma unroll
        for (int nt = 0; nt < 2; nt++)
            bfr[nt] = *(const bf16x8*)&Bs[(wn * 32 + nt * 16 + l15) * SA + q * 8];
#pragma unroll
        for (int mt = 0; mt < 4; mt++) {
            bf16x8 afr = *(const bf16x8*)&As[(wm * 64 + mt * 16 + l15) * SA + q * 8];
#pragma unroll
            for (int nt = 0; nt < 2; nt++)
                acc[mt][nt] = __builtin_amdgcn_mfma_f32_16x16x32_bf16(afr, bfr[nt],
                                                                      acc[mt][nt], 0, 0, 0);
        }
        __syncthreads();
    }
    const float SC = 1.0507009873554805f, AL = 1.6732632423543772f;
#pragma unroll
    for (int mt = 0; mt < 4; mt++) {
        int grow = rowBase + wm * 64 + mt * 16 + q * 4;
#pragma unroll
        for (int nt = 0; nt < 2; nt++) {
            int gcol = colBase + wn * 32 + nt * 16 + l15;
            if (gcol < 240) {
#pragma unroll
                for (int reg = 0; reg < 4; reg++) {
                    float v = acc[mt][nt][reg];
                    v = (v > 0.f) ? SC * v : SC * AL * (__expf(v) - 1.f);
                    out[(size_t)(grow + reg) * 240 + gcol] = v;
                }
            }
        }
    }
}

// ---------------------------------------------------------------------------
extern "C" void kernel_launch(void* const* d_in, const int* in_sizes, int n_in,
                              void* d_out, int out_size, void* d_ws, size_t ws_size,
                              hipStream_t stream) {
    const float* x = (const float*)d_in[0];
    const float* W_in = (const float*)d_in[1];
    const float* conv_w = (const float*)d_in[2];
    const float* conv_b = (const float*)d_in[3];
    const float* A_log = (const float*)d_in[4];
    const float* dt_bias = (const float*)d_in[5];
    const float* Dv = (const float*)d_in[6];
    const float* norm_w = (const float*)d_in[7];
    const float* W_out = (const float*)d_in[8];
    float* out = (float*)d_out;

    float* ws = (float*)d_ws;
    float* zxbcdt = ws;                                  // 16000*1160 f32
    float* xc = zxbcdt + (size_t)ROWS * NPROJ;           // 16000*640 f32
    float* dtp = xc + (size_t)ROWS * D_XBC;              // 16000*8 f32
    float* yout = dtp + (size_t)ROWS * NHEADS;           // 16000*512 f32

    // aliases of dead regions:
    unsigned short* a_bf = (unsigned short*)xc;          // live cast->gemm1
    unsigned short* bt_bf = a_bf + (size_t)ROWS * KPAD;  // live cast->gemm1
    unsigned short* wt_bf = (unsigned short*)dtp;        // live wcast->gemm2 (dtp dead after scan)
    unsigned short* g_bf = (unsigned short*)xc;          // live gate->gemm2 (xc dead after scan)

    int cast_total = ROWS * KPAD + NPAD * KPAD;
    cast_kernel<<<dim3((cast_total + 255) / 256), 256, 0, stream>>>(x, W_in, a_bf, bt_bf);

    gemm1_mfma<<<dim3(NPAD / 64, ROWS / 128), 256, 0, stream>>>(a_bf, bt_bf, zxbcdt);

    int conv_total = ROWS * D_XBC + ROWS * NHEADS;
    conv_kernel<<<dim3((conv_total + 255) / 256), 256, 0, stream>>>(zxbcdt, conv_w, conv_b,
                                                                    dt_bias, xc, dtp);

    scan_mfma<<<dim3(BATCH * NHEADS), 256, 0, stream>>>(xc, dtp, A_log, Dv, yout);

    wcast_kernel<<<dim3(D_INNER * D_MODEL / 256), 256, 0, stream>>>(W_out, wt_bf);

    gate_kernel<<<dim3(ROWS / 4), 256, 0, stream>>>(yout, zxbcdt, norm_w, g_bf);

    gemm2_mfma<<<dim3(D_MODEL / 64, ROWS / 128), 256, 0, stream>>>(g_bf, wt_bf, out);
}